// Round 14
// baseline (322.519 us; speedup 1.0000x reference)
//
#include <hip/hip_runtime.h>
#include <hip/hip_bf16.h>
#include <math.h>

constexpr int NB = 256;    // batch
constexpr int NS = 512;    // source positions
constexpr int ND = 1024;   // hidden
constexpr int NV = 50257;  // vocab
constexpr int NBLK = (NV + 255) / 256;     // 197 column-blocks of 256
constexpr int NTILES_D = ND / 64;          // 16

typedef __attribute__((ext_vector_type(8))) short bf16x8;
typedef __attribute__((ext_vector_type(4))) float f32x4;
typedef unsigned long long ull;

__device__ __forceinline__ short f2bf(float f) {
  unsigned u = __builtin_bit_cast(unsigned, f);
  u = (u + 0x7FFFu + ((u >> 16) & 1u)) >> 16;   // RNE
  return (short)u;
}

// 4-octet swizzle for 64B rows: <=2-way banks.
__device__ __forceinline__ int s32(int r) { return (r & 3) ^ ((r >> 2) & 3); }
// legacy 8-slot swizzle for 128B rows (gate B tile)
__device__ __forceinline__ int swz(int r) { return (r & 7) ^ ((r >> 3) & 1); }

__device__ __forceinline__ const bf16x8* frag128(const short* base, int r, int slot) {
  return reinterpret_cast<const bf16x8*>(
      reinterpret_cast<const char*>(base) + r * 128 + ((slot ^ swz(r)) << 4));
}
__device__ __forceinline__ const bf16x8* frag64(const short* base, int r, int g) {
  return reinterpret_cast<const bf16x8*>(
      reinterpret_cast<const char*>(base) + r * 64 + ((g ^ s32(r)) << 4));
}

__device__ __forceinline__ void async_copy16(const void* gsrc, void* ldsdst) {
  __builtin_amdgcn_global_load_lds(
      (const __attribute__((address_space(1))) unsigned int*)gsrc,
      (__attribute__((address_space(3))) unsigned int*)ldsdst, 16, 0, 0);
}

// Bijective XCD-chunked tile remap (kept from R13: small real win on gemm3).
__device__ __forceinline__ int xcd_tile(int o) {
  int xcd = o & 7;
  int idx = o >> 3;
  return (xcd < 5) ? xcd * 25 + idx : 125 + (xcd - 5) * 24 + idx;
}

// ---------------------------------------------------------------------------
// prep_x: xb[m][t32][phys] bf16, 32-granular, pre-swizzled for linear DMA.
// ---------------------------------------------------------------------------
__global__ __launch_bounds__(256)
void prep_x(const float* __restrict__ x, short* __restrict__ xb) {
  int idx = blockIdx.x * 256 + threadIdx.x;      // 32768 chunks
  int m = idx >> 7, t32 = (idx >> 2) & 31, p = idx & 3;
  const float4* src = reinterpret_cast<const float4*>(x + m * ND + t32 * 32 + p * 8);
  float4 f0 = src[0], f1 = src[1];
  bf16x8 v = { f2bf(f0.x), f2bf(f0.y), f2bf(f0.z), f2bf(f0.w),
               f2bf(f1.x), f2bf(f1.y), f2bf(f1.z), f2bf(f1.w) };
  *reinterpret_cast<bf16x8*>(reinterpret_cast<char*>(xb) +
      m * 2048 + t32 * 64 + ((p ^ s32(m)) << 4)) = v;
}

// ---------------------------------------------------------------------------
// gemm3f: logits GEMM + FUSED global softmax + gen output (R14).
// Loop identical to R13 (B wall is structural). Epilogue: per-block (m,s)
// partials -> grid spin-barrier (197 blocks, 1/CU, co-resident) -> every
// block combines all partials per row -> single write exp(v-m)*mix0/s.
// ---------------------------------------------------------------------------
__global__ __launch_bounds__(1024, 1)
void gemm3f(const short* __restrict__ xb, const float* __restrict__ W,
            const float* __restrict__ bias, const float* __restrict__ mix,
            float* __restrict__ out, unsigned* __restrict__ cnt,
            ull* __restrict__ partials) {
  __shared__ __align__(16) short As[2][256 * 32];   // 2 x 16 KB
  __shared__ __align__(16) float Braw[2][32 * 256]; // 2 x 32 KB
  __shared__ __align__(16) short Bs[2][256 * 32];   // 2 x 16 KB
  const int tid = threadIdx.x;
  const int lane = tid & 63, w = tid >> 6;
  const int wr = w >> 2, wc = w & 3;
  const int g = lane >> 4, c16 = lane & 15;
  const int tile = xcd_tile(blockIdx.x);
  const int n0 = tile * 256;

  const int tn = tid & 255, to = tid >> 8;       // transpose identity

  f32x4 acc[4][4] = {};

  auto issueA = [&](int t, short* dstA) {
    int c = tid;
    int m = c >> 2, p = c & 3;
    const char* src = reinterpret_cast<const char*>(xb) +
        m * 2048 + t * 64 + (p << 4);
    async_copy16(src, reinterpret_cast<char*>(dstA) + (c << 4));
  };
  auto issueB = [&](int t, float* dstB) {
#pragma unroll
    for (int j = 0; j < 2; ++j) {
      int r = w * 2 + j;                         // 0..31
      int gc = n0 + lane * 4;
      if (gc > NV - 4) gc = NV - 4;              // clamp (tail tile)
      const float* src = W + (size_t)(t * 32 + r) * NV + gc;
      async_copy16(src, reinterpret_cast<char*>(dstB) + r * 1024 + lane * 16);
    }
  };
  auto transposeB = [&](const float* srcB, short* dstB) {
    float v[8];
    bool ok = (n0 + tn) < NV;
#pragma unroll
    for (int j = 0; j < 8; ++j)
      v[j] = ok ? srcB[(to * 8 + j) * 256 + tn] : 0.f;
    bf16x8 q = { f2bf(v[0]), f2bf(v[1]), f2bf(v[2]), f2bf(v[3]),
                 f2bf(v[4]), f2bf(v[5]), f2bf(v[6]), f2bf(v[7]) };
    *reinterpret_cast<bf16x8*>(reinterpret_cast<char*>(dstB) +
        tn * 64 + ((to ^ s32(tn)) << 4)) = q;
  };
  auto compute = [&](const short* A_, const short* B_) {
    bf16x8 b[4];
#pragma unroll
    for (int ni = 0; ni < 4; ++ni) b[ni] = *frag64(B_, wc * 64 + ni * 16 + c16, g);
#pragma unroll
    for (int mi = 0; mi < 4; ++mi) {
      bf16x8 a = *frag64(A_, wr * 64 + mi * 16 + c16, g);
#pragma unroll
      for (int ni = 0; ni < 4; ++ni)
        acc[mi][ni] = __builtin_amdgcn_mfma_f32_16x16x32_bf16(a, b[ni], acc[mi][ni], 0, 0, 0);
    }
  };

  // ---- prologue ----
  issueA(0, As[0]);
  issueB(0, Braw[0]);
  issueB(1, Braw[1]);
  asm volatile("s_waitcnt vmcnt(2)" ::: "memory");
  __builtin_amdgcn_s_barrier();
  transposeB(Braw[0], Bs[0]);
  asm volatile("s_waitcnt lgkmcnt(0)" ::: "memory");
  __builtin_amdgcn_s_barrier();

#pragma unroll 1
  for (int t = 0; t < 32; ++t) {
    const int tA = (t + 1 < 32) ? t + 1 : 31;
    const int tB = (t + 2 < 32) ? t + 2 : 31;
    issueA(tA, As[(t + 1) & 1]);
    asm volatile("" ::: "memory");
    issueB(tB, Braw[t & 1]);
    asm volatile("s_waitcnt vmcnt(3)" ::: "memory");
    __builtin_amdgcn_s_barrier();
    if (t + 1 < 32) transposeB(Braw[(t + 1) & 1], Bs[(t + 1) & 1]);
    compute(As[t & 1], Bs[t & 1]);
    asm volatile("s_waitcnt lgkmcnt(0)" ::: "memory");
    __builtin_amdgcn_s_barrier();
  }

  // ---- phase 1: per-block row stats (m,s) -> LDS merge (alias As) ----
  float* ssm = reinterpret_cast<float*>(&As[0][0]);   // [256][4]
  float* sss = ssm + 256 * 4;                         // [256][4]
#pragma unroll
  for (int mi = 0; mi < 4; ++mi) {
#pragma unroll
    for (int r = 0; r < 4; ++r) {
      int row = wr * 64 + mi * 16 + g * 4 + r;
      float vals[4];
      float pm = -3.0e38f, ps = 0.f;
#pragma unroll
      for (int ni = 0; ni < 4; ++ni) {
        int col = n0 + wc * 64 + ni * 16 + c16;
        if (col < NV) {
          float v = acc[mi][ni][r] + bias[col];
          vals[ni] = v;
          pm = fmaxf(pm, v);
        }
      }
#pragma unroll
      for (int ni = 0; ni < 4; ++ni) {
        int col = n0 + wc * 64 + ni * 16 + c16;
        if (col < NV) ps += expf(vals[ni] - pm);
      }
#pragma unroll
      for (int o = 1; o < 16; o <<= 1) {
        float m2 = __shfl_xor(pm, o, 64);
        float s2 = __shfl_xor(ps, o, 64);
        float mn = fmaxf(pm, m2);
        ps = ps * expf(pm - mn) + s2 * expf(m2 - mn);
        pm = mn;
      }
      if (c16 == 0) { ssm[row * 4 + wc] = pm; sss[row * 4 + wc] = ps; }
    }
  }
  __syncthreads();

  // merge 4 wc-tiles, publish one partial per (row, block)
  if (tid < 256) {
    int row = tid;
    float m = ssm[row * 4], s = sss[row * 4];
#pragma unroll
    for (int k = 1; k < 4; ++k) {
      float m2 = ssm[row * 4 + k], s2 = sss[row * 4 + k];
      float mn = fmaxf(m, m2);
      s = s * expf(m - mn) + s2 * expf(m2 - mn);
      m = mn;
    }
    float2 p; p.x = m; p.y = s;
    partials[(size_t)row * NBLK + blockIdx.x] = __builtin_bit_cast(ull, p);
  }
  // ---- grid barrier (R8-proven) ----
  __threadfence();
  __syncthreads();
  if (tid == 0) {
    atomicAdd(cnt, 1u);
    while (__hip_atomic_load(cnt, __ATOMIC_RELAXED, __HIP_MEMORY_SCOPE_AGENT) <
           gridDim.x)
      __builtin_amdgcn_s_sleep(16);
  }
  __syncthreads();
  __threadfence();

  // ---- phase 2: every block combines all partials per row ----
  {
    int row = tid >> 2, q = tid & 3;
    int b0 = q * 50;
    int b1 = (q == 3) ? NBLK : b0 + 50;
    float m = -3.0e38f, s = 0.f;
    for (int b = b0; b < b1; ++b) {
      ull u = __hip_atomic_load(&partials[(size_t)row * NBLK + b],
                                __ATOMIC_RELAXED, __HIP_MEMORY_SCOPE_AGENT);
      float2 p = __builtin_bit_cast(float2, u);
      float mn = fmaxf(m, p.x);
      s = s * expf(m - mn) + p.y * expf(p.x - mn);
      m = mn;
    }
#pragma unroll
    for (int o = 1; o < 4; o <<= 1) {
      float m2 = __shfl_xor(m, o, 64);
      float s2 = __shfl_xor(s, o, 64);
      float mn = fmaxf(m, m2);
      s = s * expf(m - mn) + s2 * expf(m2 - mn);
      m = mn;
    }
    if (q == 0) {
      ssm[row] = m;
      sss[row] = mix[row * 2 + 0] / s;          // scale = mix0 / sum
    }
  }
  __syncthreads();

  // ---- phase 3: single final write ----
#pragma unroll
  for (int mi = 0; mi < 4; ++mi) {
#pragma unroll
    for (int r = 0; r < 4; ++r) {
      int row = wr * 64 + mi * 16 + g * 4 + r;
      float m = ssm[row], scale = sss[row];
#pragma unroll
      for (int ni = 0; ni < 4; ++ni) {
        int col = n0 + wc * 64 + ni * 16 + c16;
        if (col < NV) {
          float v = acc[mi][ni][r] + bias[col];
          out[(size_t)row * NV + col] = expf(v - m) * scale;
        }
      }
    }
  }
}

// ---------------------------------------------------------------------------
// gate GEMM: h = tanh(x @ W1 + b1). BM=256, BN=64, BK=64, 256 thr, 16 blocks.
// ---------------------------------------------------------------------------
__device__ __forceinline__ void gloadA8g(const short* __restrict__ xb,
                                         int w, int lane, int t, short* AsN) {
#pragma unroll
  for (int j = 0; j < 8; ++j) {
    int c = (w * 8 + j) * 64 + lane;             // 0..2047
    int m = c >> 3, q = c & 7;
    int kk = q >> 2, p = q & 3;
    const char* src = reinterpret_cast<const char*>(xb) +
        m * 2048 + (t * 2 + kk) * 64 + (p << 4);
    async_copy16(src, reinterpret_cast<char*>(AsN) + ((w * 8 + j) << 10));
  }
}

__device__ __forceinline__ void loadBg(const float* __restrict__ W, int N, bool okc,
                                       int n0, int w, int lane, int t, float v[16]) {
#pragma unroll
  for (int i = 0; i < 16; ++i)
    v[i] = okc ? W[(size_t)(t * 64 + w * 16 + i) * N + n0 + lane] : 0.f;
}

__device__ __forceinline__ void transBg(const float v[16], short* BsN, int w, int lane) {
  bf16x8 lo = { f2bf(v[0]), f2bf(v[1]), f2bf(v[2]), f2bf(v[3]),
                f2bf(v[4]), f2bf(v[5]), f2bf(v[6]), f2bf(v[7]) };
  bf16x8 hi = { f2bf(v[8]), f2bf(v[9]), f2bf(v[10]), f2bf(v[11]),
                f2bf(v[12]), f2bf(v[13]), f2bf(v[14]), f2bf(v[15]) };
  char* row = reinterpret_cast<char*>(BsN) + lane * 128;
  *reinterpret_cast<bf16x8*>(row + (((w * 2 + 0) ^ swz(lane)) << 4)) = lo;
  *reinterpret_cast<bf16x8*>(row + (((w * 2 + 1) ^ swz(lane)) << 4)) = hi;
}

__device__ __forceinline__ void computeStepG(const short* A, const short* B,
                                             int w, int g, int c16, f32x4 acc[4][4]) {
#pragma unroll
  for (int kk = 0; kk < 2; ++kk) {
    int slot = kk * 4 + g;
    bf16x8 b[4];
#pragma unroll
    for (int ni = 0; ni < 4; ++ni) b[ni] = *frag128(B, ni * 16 + c16, slot);
#pragma unroll
    for (int mi = 0; mi < 4; ++mi) {
      int r = w * 64 + mi * 16 + c16;
      bf16x8 a = *reinterpret_cast<const bf16x8*>(
          reinterpret_cast<const char*>(A) + r * 128 +
          ((kk * 4 + (g ^ s32(r))) << 4));
#pragma unroll
      for (int ni = 0; ni < 4; ++ni)
        acc[mi][ni] = __builtin_amdgcn_mfma_f32_16x16x32_bf16(a, b[ni], acc[mi][ni], 0, 0, 0);
    }
  }
}

__global__ __launch_bounds__(256, 3)
void gemm_gate(const short* __restrict__ xb, const float* __restrict__ W,
               const float* __restrict__ bias, float* __restrict__ Cout, int N) {
  __shared__ __align__(16) short As[256 * 64];   // 32 KB
  __shared__ __align__(16) short Bs[64 * 64];    // 8 KB
  const int tid = threadIdx.x;
  const int lane = tid & 63, w = tid >> 6;
  const int g = lane >> 4, c16 = lane & 15;
  const int n0 = blockIdx.x * 64;
  const bool okc = (n0 + lane) < N;

  f32x4 acc[4][4] = {};
  float vbA[16], vbN[16];
  loadBg(W, N, okc, n0, w, lane, 0, vbA);

#pragma unroll 1
  for (int t = 0; t < 16; ++t) {
    asm volatile("" ::: "memory");
    __builtin_amdgcn_s_barrier();
    asm volatile("" ::: "memory");
    gloadA8g(xb, w, lane, t, As);
    asm volatile("" ::: "memory");
    int tn2 = (t < 15) ? t + 1 : 15;
    loadBg(W, N, okc, n0, w, lane, tn2, vbN);
    transBg(vbA, Bs, w, lane);
    asm volatile("s_waitcnt vmcnt(16) lgkmcnt(0)" ::: "memory");
    __builtin_amdgcn_s_barrier();
    asm volatile("" ::: "memory");
    computeStepG(As, Bs, w, g, c16, acc);
#pragma unroll
    for (int i = 0; i < 16; ++i) vbA[i] = vbN[i];
  }

#pragma unroll
  for (int mi = 0; mi < 4; ++mi)
#pragma unroll
    for (int r = 0; r < 4; ++r) {
      int row = w * 64 + mi * 16 + g * 4 + r;
#pragma unroll
      for (int ni = 0; ni < 4; ++ni) {
        int col = n0 + ni * 16 + c16;
        if (col < N)
          Cout[(size_t)row * N + col] = tanhf(acc[mi][ni][r] + bias[col]);
      }
    }
}

// ---------------------------------------------------------------------------
// mix = softmax2(h @ W2 + b2), one block per row
// ---------------------------------------------------------------------------
__global__ __launch_bounds__(256)
void gate_mix(const float* __restrict__ h, const float* __restrict__ W2,
              const float* __restrict__ b2, float* __restrict__ mix) {
  const int row = blockIdx.x;
  const int tid = threadIdx.x;
  float g0 = 0.f, g1 = 0.f;
  for (int j = tid; j < ND; j += 256) {
    float hv = h[row * ND + j];
    g0 += hv * W2[j * 2 + 0];
    g1 += hv * W2[j * 2 + 1];
  }
  for (int o = 32; o > 0; o >>= 1) {
    g0 += __shfl_down(g0, o, 64);
    g1 += __shfl_down(g1, o, 64);
  }
  __shared__ float l0[4], l1[4];
  int wid = tid >> 6, lane = tid & 63;
  if (lane == 0) { l0[wid] = g0; l1[wid] = g1; }
  __syncthreads();
  if (tid == 0) {
    float a = l0[0] + l0[1] + l0[2] + l0[3] + b2[0];
    float c = l1[0] + l1[1] + l1[2] + l1[3] + b2[1];
    float m = fmaxf(a, c);
    float e0 = expf(a - m), e1 = expf(c - m);
    float inv = 1.f / (e0 + e1);
    mix[row * 2 + 0] = e0 * inv;
    mix[row * 2 + 1] = e1 * inv;
  }
}

// ---------------------------------------------------------------------------
// alphas = softmax(scores) rowwise
// ---------------------------------------------------------------------------
__global__ __launch_bounds__(256)
void softmax_scores(const float* __restrict__ scores, float* __restrict__ alphas) {
  const int row = blockIdx.x;
  const int tid = threadIdx.x;
  float v0 = scores[row * NS + tid];
  float v1 = scores[row * NS + tid + 256];
  float m = fmaxf(v0, v1);
  for (int o = 32; o > 0; o >>= 1) m = fmaxf(m, __shfl_down(m, o, 64));
  __shared__ float lm[4], ls[4];
  int wid = tid >> 6, lane = tid & 63;
  if (lane == 0) lm[wid] = m;
  __syncthreads();
  float mAll = fmaxf(fmaxf(lm[0], lm[1]), fmaxf(lm[2], lm[3]));
  float e0 = expf(v0 - mAll), e1 = expf(v1 - mAll);
  float s = e0 + e1;
  for (int o = 32; o > 0; o >>= 1) s += __shfl_down(s, o, 64);
  if (lane == 0) ls[wid] = s;
  __syncthreads();
  float inv = 1.f / (ls[0] + ls[1] + ls[2] + ls[3]);
  alphas[row * NS + tid] = e0 * inv;
  alphas[row * NS + tid + 256] = e1 * inv;
}

// ---------------------------------------------------------------------------
// out[row, ctx_ids[row,s]] += alphas[row,s] * mix1[row]
// ---------------------------------------------------------------------------
__global__ __launch_bounds__(512)
void scatter_copy(float* __restrict__ out, const float* __restrict__ alphas,
                  const int* __restrict__ ids, const float* __restrict__ mix) {
  const int row = blockIdx.x;
  const int t = threadIdx.x;
  float a = alphas[row * NS + t] * mix[row * 2 + 1];
  atomicAdd(&out[(size_t)row * NV + ids[row * NS + t]], a);
}

extern "C" void kernel_launch(void* const* d_in, const int* in_sizes, int n_in,
                              void* d_out, int out_size, void* d_ws, size_t ws_size,
                              hipStream_t stream) {
  const float* x      = (const float*)d_in[0];
  const float* scores = (const float*)d_in[1];
  const int*   ctx    = (const int*)d_in[2];
  const float* Wg     = (const float*)d_in[3];
  const float* bg     = (const float*)d_in[4];
  const float* W1     = (const float*)d_in[5];
  const float* b1     = (const float*)d_in[6];
  const float* W2     = (const float*)d_in[7];
  const float* b2     = (const float*)d_in[8];
  float* out = (float*)d_out;

  short*    xb       = (short*)d_ws;                               // 512 KB
  unsigned* cnt      = (unsigned*)((char*)d_ws + 512 * 1024);      // 64 B slot
  ull*      partials = (ull*)((char*)d_ws + 512 * 1024 + 64);      // 256*197*8
  float*    mix      = (float*)((char*)partials + (size_t)NB * NBLK * 8);
  float*    alphas   = mix + NB * 2;
  float*    h        = alphas + NB * NS;

  // x -> bf16, 32-granular pre-swizzled layout
  prep_x<<<128, 256, 0, stream>>>(x, xb);
  // h = tanh(x @ W1 + b1)
  gemm_gate<<<NTILES_D, 256, 0, stream>>>(xb, W1, b1, h, ND);
  // mix = softmax2(h @ W2 + b2)
  gate_mix<<<NB, 256, 0, stream>>>(h, W2, b2, mix);
  // alphas = softmax(scores)
  softmax_scores<<<NB, 256, 0, stream>>>(scores, alphas);
  // reset grid-barrier counter; fused logits GEMM + softmax + gen output
  hipMemsetAsync(cnt, 0, sizeof(unsigned), stream);
  gemm3f<<<NBLK, 1024, 0, stream>>>(xb, Wg, bg, mix, out, cnt, partials);
  // copy distribution scatter
  scatter_copy<<<NB, NS, 0, stream>>>(out, alphas, ctx, mix);
}

// Round 15
// 125.838 us; speedup vs baseline: 2.5630x; 2.5630x over previous
//
#include <hip/hip_runtime.h>
#include <hip/hip_bf16.h>
#include <math.h>

constexpr int NB = 256;    // batch
constexpr int NS = 512;    // source positions
constexpr int ND = 1024;   // hidden
constexpr int NV = 50257;  // vocab
constexpr int NBLK = (NV + 255) / 256;     // 197 column-blocks of 256
constexpr int NTILE2 = NBLK * 4;           // 788 partial 64-col tiles per row

typedef __attribute__((ext_vector_type(8))) short bf16x8;
typedef __attribute__((ext_vector_type(4))) float f32x4;

__device__ __forceinline__ short f2bf(float f) {
  unsigned u = __builtin_bit_cast(unsigned, f);
  u = (u + 0x7FFFu + ((u >> 16) & 1u)) >> 16;   // RNE
  return (short)u;
}

// 4-octet swizzle for 64B rows: <=2-way banks.
__device__ __forceinline__ int s32(int r) { return (r & 3) ^ ((r >> 2) & 3); }

__device__ __forceinline__ const bf16x8* frag64(const short* base, int r, int g) {
  return reinterpret_cast<const bf16x8*>(
      reinterpret_cast<const char*>(base) + r * 64 + ((g ^ s32(r)) << 4));
}

__device__ __forceinline__ void async_copy16(const void* gsrc, void* ldsdst) {
  __builtin_amdgcn_global_load_lds(
      (const __attribute__((address_space(1))) unsigned int*)gsrc,
      (__attribute__((address_space(3))) unsigned int*)ldsdst, 16, 0, 0);
}

// Bijective XCD-chunked tile remap (R13-proven small win on logits blocks).
__device__ __forceinline__ int xcd_tile(int o) {
  int xcd = o & 7;
  int idx = o >> 3;
  return (xcd < 5) ? xcd * 25 + idx : 125 + (xcd - 5) * 24 + idx;
}

// ---------------------------------------------------------------------------
// prep_x: xb[m][t32][phys] bf16, 32-granular, pre-swizzled for linear DMA.
// ---------------------------------------------------------------------------
__global__ __launch_bounds__(256)
void prep_x(const float* __restrict__ x, short* __restrict__ xb) {
  int idx = blockIdx.x * 256 + threadIdx.x;      // 32768 chunks
  int m = idx >> 7, t32 = (idx >> 2) & 31, p = idx & 3;
  const float4* src = reinterpret_cast<const float4*>(x + m * ND + t32 * 32 + p * 8);
  float4 f0 = src[0], f1 = src[1];
  bf16x8 v = { f2bf(f0.x), f2bf(f0.y), f2bf(f0.z), f2bf(f0.w),
               f2bf(f1.x), f2bf(f1.y), f2bf(f1.z), f2bf(f1.w) };
  *reinterpret_cast<bf16x8*>(reinterpret_cast<char*>(xb) +
      m * 2048 + t32 * 64 + ((p ^ s32(m)) << 4)) = v;
}

// ---------------------------------------------------------------------------
// biggemm (R15): one launch, 201 blocks.
//   blocks [0,197): logits tiles (W=Wg, N=NV, raw C + per-row partials) —
//                   loop byte-identical to R13's proven gemm3.
//   blocks [197,201): gate tiles (W=W1, N=ND, tanh -> h) — same loop, runs
//                   concurrently on otherwise-idle CUs (201 <= 256).
// ---------------------------------------------------------------------------
__global__ __launch_bounds__(1024, 1)
void biggemm(const short* __restrict__ xb,
             const float* __restrict__ Wg, const float* __restrict__ bg,
             const float* __restrict__ W1, const float* __restrict__ b1,
             float* __restrict__ out, float* __restrict__ h,
             float* __restrict__ partials) {
  __shared__ __align__(16) short As[2][256 * 32];   // 2 x 16 KB
  __shared__ __align__(16) float Braw[2][32 * 256]; // 2 x 32 KB
  __shared__ __align__(16) short Bs[2][256 * 32];   // 2 x 16 KB
  const int tid = threadIdx.x;
  const int lane = tid & 63, w = tid >> 6;
  const int wr = w >> 2, wc = w & 3;
  const int g = lane >> 4, c16 = lane & 15;

  const bool gate = blockIdx.x >= NBLK;            // block-uniform
  const float* W    = gate ? W1 : Wg;
  const float* bias = gate ? b1 : bg;
  const int ldN  = gate ? ND : NV;
  const int tile = gate ? (int)(blockIdx.x - NBLK) : xcd_tile(blockIdx.x);
  const int n0 = tile * 256;

  const int tn = tid & 255, to = tid >> 8;         // transpose identity

  f32x4 acc[4][4] = {};

  auto issueA = [&](int t, short* dstA) {
    int c = tid;
    int m = c >> 2, p = c & 3;
    const char* src = reinterpret_cast<const char*>(xb) +
        m * 2048 + t * 64 + (p << 4);
    async_copy16(src, reinterpret_cast<char*>(dstA) + (c << 4));
  };
  auto issueB = [&](int t, float* dstB) {
#pragma unroll
    for (int j = 0; j < 2; ++j) {
      int r = w * 2 + j;                           // 0..31
      int gc = n0 + lane * 4;
      if (gc > ldN - 4) gc = ldN - 4;              // clamp (tail tile)
      const float* src = W + (size_t)(t * 32 + r) * ldN + gc;
      async_copy16(src, reinterpret_cast<char*>(dstB) + r * 1024 + lane * 16);
    }
  };
  auto transposeB = [&](const float* srcB, short* dstB) {
    float v[8];
    bool ok = (n0 + tn) < ldN;
#pragma unroll
    for (int j = 0; j < 8; ++j)
      v[j] = ok ? srcB[(to * 8 + j) * 256 + tn] : 0.f;
    bf16x8 q = { f2bf(v[0]), f2bf(v[1]), f2bf(v[2]), f2bf(v[3]),
                 f2bf(v[4]), f2bf(v[5]), f2bf(v[6]), f2bf(v[7]) };
    *reinterpret_cast<bf16x8*>(reinterpret_cast<char*>(dstB) +
        tn * 64 + ((to ^ s32(tn)) << 4)) = q;
  };
  auto compute = [&](const short* A_, const short* B_) {
    bf16x8 b[4];
#pragma unroll
    for (int ni = 0; ni < 4; ++ni) b[ni] = *frag64(B_, wc * 64 + ni * 16 + c16, g);
#pragma unroll
    for (int mi = 0; mi < 4; ++mi) {
      bf16x8 a = *frag64(A_, wr * 64 + mi * 16 + c16, g);
#pragma unroll
      for (int ni = 0; ni < 4; ++ni)
        acc[mi][ni] = __builtin_amdgcn_mfma_f32_16x16x32_bf16(a, b[ni], acc[mi][ni], 0, 0, 0);
    }
  };

  // ---- prologue ----
  issueA(0, As[0]);
  issueB(0, Braw[0]);
  issueB(1, Braw[1]);
  asm volatile("s_waitcnt vmcnt(2)" ::: "memory");   // drain A0+B0, keep B1
  __builtin_amdgcn_s_barrier();
  transposeB(Braw[0], Bs[0]);
  asm volatile("s_waitcnt lgkmcnt(0)" ::: "memory");
  __builtin_amdgcn_s_barrier();

#pragma unroll 1
  for (int t = 0; t < 32; ++t) {
    const int tA = (t + 1 < 32) ? t + 1 : 31;      // clamped re-issues keep
    const int tB = (t + 2 < 32) ? t + 2 : 31;      // vmcnt accounting uniform
    issueA(tA, As[(t + 1) & 1]);                   // 1 DMA
    asm volatile("" ::: "memory");
    issueB(tB, Braw[t & 1]);                       // 2 DMA
    asm volatile("s_waitcnt vmcnt(3)" ::: "memory"); // A(t)+B(t+1) landed
    __builtin_amdgcn_s_barrier();
    if (t + 1 < 32) transposeB(Braw[(t + 1) & 1], Bs[(t + 1) & 1]);
    compute(As[t & 1], Bs[t & 1]);
    asm volatile("s_waitcnt lgkmcnt(0)" ::: "memory");
    __builtin_amdgcn_s_barrier();
  }

  // ---- epilogue: C/D layout col = lane&15, row = (lane>>4)*4 + reg ----
  if (gate) {
#pragma unroll
    for (int mi = 0; mi < 4; ++mi)
#pragma unroll
      for (int r = 0; r < 4; ++r) {
        int row = wr * 64 + mi * 16 + g * 4 + r;
#pragma unroll
        for (int ni = 0; ni < 4; ++ni) {
          int col = n0 + wc * 64 + ni * 16 + c16;  // always < ND
          h[(size_t)row * ND + col] = tanhf(acc[mi][ni][r] + bias[col]);
        }
      }
  } else {
#pragma unroll
    for (int mi = 0; mi < 4; ++mi) {
#pragma unroll
      for (int r = 0; r < 4; ++r) {
        int row = wr * 64 + mi * 16 + g * 4 + r;
        float vals[4];
        float pm = -3.0e38f;
#pragma unroll
        for (int ni = 0; ni < 4; ++ni) {
          int col = n0 + wc * 64 + ni * 16 + c16;
          bool ok2 = col < NV;
          float bv = ok2 ? bias[col] : 0.f;
          float v = acc[mi][ni][r] + bv;
          vals[ni] = v;
          if (ok2) {
            out[(size_t)row * NV + col] = v;
            pm = fmaxf(pm, v);
          }
        }
        float ps = 0.f;
#pragma unroll
        for (int ni = 0; ni < 4; ++ni) {
          int col = n0 + wc * 64 + ni * 16 + c16;
          if (col < NV) ps += expf(vals[ni] - pm);
        }
#pragma unroll
        for (int o = 1; o < 16; o <<= 1) {
          float m2 = __shfl_xor(pm, o, 64);
          float s2 = __shfl_xor(ps, o, 64);
          float mn = fmaxf(pm, m2);
          ps = ps * expf(pm - mn) + s2 * expf(m2 - mn);
          pm = mn;
        }
        if (c16 == 0) {
          size_t idx = (size_t)row * NTILE2 + tile * 4 + wc;
          partials[idx * 2 + 0] = pm;
          partials[idx * 2 + 1] = ps;
        }
      }
    }
  }
}

// ---------------------------------------------------------------------------
// postpass (R15): one block per row, 1024 threads. Fuses softmax(scores),
// gate mix, partials combine, softmax-finalize of logits, and copy-scatter.
// ---------------------------------------------------------------------------
__global__ __launch_bounds__(1024)
void postpass(const float* __restrict__ scores, const int* __restrict__ ctx,
              const float* __restrict__ h, const float* __restrict__ W2,
              const float* __restrict__ b2, const float* __restrict__ partials,
              float* __restrict__ out) {
  const int row = blockIdx.x;
  const int tid = threadIdx.x;
  const int lane = tid & 63, wv = tid >> 6;

  __shared__ float redA[16], redB[16], redC[16], redD[16];
  __shared__ float alphas_s[NS];

  // ---- phase A: alphas = softmax(scores[row]) ----
  float v = (tid < NS) ? scores[row * NS + tid] : -3.0e38f;
  float m = v;
#pragma unroll
  for (int o = 32; o; o >>= 1) m = fmaxf(m, __shfl_xor(m, o, 64));
  if (lane == 0) redA[wv] = m;
  __syncthreads();
  float M = redA[0];
#pragma unroll
  for (int i = 1; i < 16; ++i) M = fmaxf(M, redA[i]);
  float e = (tid < NS) ? expf(v - M) : 0.f;
  float s = e;
#pragma unroll
  for (int o = 32; o; o >>= 1) s += __shfl_xor(s, o, 64);
  if (lane == 0) redB[wv] = s;
  __syncthreads();
  float S = 0.f;
#pragma unroll
  for (int i = 0; i < 16; ++i) S += redB[i];
  if (tid < NS) alphas_s[tid] = e / S;

  // ---- phase B: mix = softmax2(h[row] @ W2 + b2) ----
  float hv = h[(size_t)row * ND + tid];
  float g0 = hv * W2[tid * 2 + 0];
  float g1 = hv * W2[tid * 2 + 1];
#pragma unroll
  for (int o = 32; o; o >>= 1) {
    g0 += __shfl_xor(g0, o, 64);
    g1 += __shfl_xor(g1, o, 64);
  }
  __syncthreads();                                  // redA/redB reuse hazard
  if (lane == 0) { redA[wv] = g0; redB[wv] = g1; }
  __syncthreads();
  float A = b2[0], C = b2[1];
#pragma unroll
  for (int i = 0; i < 16; ++i) { A += redA[i]; C += redB[i]; }
  float mm = fmaxf(A, C);
  float e0 = expf(A - mm), e1 = expf(C - mm);
  float inv = 1.f / (e0 + e1);
  float mix0 = e0 * inv, mix1 = e1 * inv;

  // ---- phase C: combine partials[row][0..787] -> (FM, FS) ----
  float pm = -3.0e38f, ps = 0.f;
  if (tid < NTILE2) {
    pm = partials[((size_t)row * NTILE2 + tid) * 2 + 0];
    ps = partials[((size_t)row * NTILE2 + tid) * 2 + 1];
  }
#pragma unroll
  for (int o = 32; o; o >>= 1) {
    float m2 = __shfl_xor(pm, o, 64);
    float s2 = __shfl_xor(ps, o, 64);
    float mn = fmaxf(pm, m2);
    ps = ps * expf(pm - mn) + s2 * expf(m2 - mn);
    pm = mn;
  }
  if (lane == 0) { redC[wv] = pm; redD[wv] = ps; }
  __syncthreads();
  float FM = -3.0e38f, FS = 0.f;
#pragma unroll
  for (int i = 0; i < 16; ++i) {
    float mn = fmaxf(FM, redC[i]);
    FS = FS * expf(FM - mn) + redD[i] * expf(redC[i] - mn);
    FM = mn;
  }
  float scale = mix0 / FS;

  // ---- phase D: out[row] = exp(v - FM) * scale (in place) ----
  for (int c = tid; c < NV; c += 1024) {
    float val = out[(size_t)row * NV + c];
    out[(size_t)row * NV + c] = expf(val - FM) * scale;
  }
  __syncthreads();   // drains stores (vmcnt 0) before same-row atomics

  // ---- phase E: scatter copy distribution ----
  if (tid < NS) {
    float a = alphas_s[tid] * mix1;
    atomicAdd(&out[(size_t)row * NV + ctx[row * NS + tid]], a);
  }
}

extern "C" void kernel_launch(void* const* d_in, const int* in_sizes, int n_in,
                              void* d_out, int out_size, void* d_ws, size_t ws_size,
                              hipStream_t stream) {
  const float* x      = (const float*)d_in[0];
  const float* scores = (const float*)d_in[1];
  const int*   ctx    = (const int*)d_in[2];
  const float* Wg     = (const float*)d_in[3];
  const float* bg     = (const float*)d_in[4];
  const float* W1     = (const float*)d_in[5];
  const float* b1     = (const float*)d_in[6];
  const float* W2     = (const float*)d_in[7];
  const float* b2     = (const float*)d_in[8];
  float* out = (float*)d_out;

  short* xb       = (short*)d_ws;                                   // 512 KB
  float* partials = (float*)((char*)d_ws + 512 * 1024);             // 256*788*2 f32
  float* h        = partials + (size_t)NB * NTILE2 * 2;             // 256*1024 f32

  // x -> bf16, 32-granular pre-swizzled layout
  prep_x<<<128, 256, 0, stream>>>(x, xb);
  // logits GEMM (197 blocks) + gate GEMM (4 blocks), one launch
  biggemm<<<NBLK + 4, 1024, 0, stream>>>(xb, Wg, bg, W1, b1, out, h, partials);
  // per-row: alphas + mix + combine + finalize + scatter
  postpass<<<NB, 1024, 0, stream>>>(scores, ctx, h, W2, b2, partials, out);
}